// Round 6
// baseline (2429.933 us; speedup 1.0000x reference)
//
#include <hip/hip_runtime.h>
#include <stdint.h>

#define TT     150
#define INSZ   120
#define HID    1024
#define OUTN   35
#define NBR    8
#define TP     152      // padded time steps (= 19*8); mask row = 1216 B
#define CH     8
#define NCHUNK 19

// ---------------- ws map (bytes) — aliased, peak 8.78 MB ----------------
// SA: s1m (layer1 out) then s3m (layer3 out)   [1024][152] u64 = 1,245,184
// SB: s2m                                       1,245,184
// PK: pack slot, sequentially PK1 (1 MB) / PK2 / PK3 (6,291,456)
// XT: xT2 [120][64][152] f32 = 4,669,440 (inside PK tail, dead before PK2)
// Y : [150][35][64] f32 over dead PK after layer3
#define SA_OFF   0
#define SB_OFF   1245184
#define PK_OFF   2490368
#define XT_OFF   3538944
#define Y_OFF    2490368
#define ACC_OFF  3866624

// ---- pack masked rows into {idx u16[NNZ_OUT], w f32[NNZ_OUT]} streams ----
template <int DIN, int NNZ_EXPECT, int NNZ_OUT, int RSTRIDE, int WOFF>
__global__ __launch_bounds__(512) void k_pack(
    const float* __restrict__ w, const void* __restrict__ maskp,
    uint8_t* __restrict__ dst) {
    const int lane = threadIdx.x & 63;
    const int wid  = __builtin_amdgcn_readfirstlane(threadIdx.x >> 6);
    const int r    = blockIdx.x * 8 + wid;
    uint16_t* di = (uint16_t*)(dst + (size_t)r * RSTRIDE);
    float*    dw = (float*)(dst + (size_t)r * RSTRIDE + WOFF);
    const unsigned char* m8  = (const unsigned char*)maskp;
    const int*           m32 = (const int*)maskp;

    int cnt = 0;
    for (int c = 0; c * 64 < DIN; ++c) {
        const int i = c * 64 + lane;
        int   mv = 0; float wv = 0.f;
        if (i < DIN) { mv = m8[(size_t)r * DIN + i]; wv = w[(size_t)r * DIN + i]; }
        const unsigned long long bal = __ballot(mv != 0);
        const int pos = __popcll(bal & ((1ull << lane) - 1ull));
        if (mv && cnt + pos < NNZ_OUT) { di[cnt + pos] = (uint16_t)i; dw[cnt + pos] = wv; }
        cnt += __popcll(bal);
    }
    if (cnt != NNZ_EXPECT) {          // masks are int32 after all
        cnt = 0;
        for (int c = 0; c * 64 < DIN; ++c) {
            const int i = c * 64 + lane;
            int   mv = 0; float wv = 0.f;
            if (i < DIN) { mv = m32[(size_t)r * DIN + i]; wv = w[(size_t)r * DIN + i]; }
            const unsigned long long bal = __ballot(mv != 0);
            const int pos = __popcll(bal & ((1ull << lane) - 1ull));
            if (mv && cnt + pos < NNZ_OUT) { di[cnt + pos] = (uint16_t)i; dw[cnt + pos] = wv; }
            cnt += __popcll(bal);
        }
    }
    for (int f = cnt + lane; f < NNZ_OUT; f += 64) { di[f] = 0; dw[f] = 0.f; }
}

// x[b][0][t][i] -> xT2[i][b][t] (TP-padded, pad zeroed). 570*256 = 145920
__global__ __launch_bounds__(256) void k_tx2(const float* __restrict__ x,
                                             float* __restrict__ xT2) {
    const int e = blockIdx.x * 256 + threadIdx.x;   // (chunk, b, i)
    const int c = e / 7680;
    const int rem = e - c * 7680;
    const int b = rem / INSZ, i = rem - b * INSZ;
    float v[CH];
#pragma unroll
    for (int k = 0; k < CH; ++k) {
        const int t = c * CH + k;
        v[k] = (t < TT) ? x[((size_t)b * TT + t) * INSZ + i] : 0.f;
    }
    float* dst = xT2 + ((size_t)i * 64 + b) * TP + c * CH;
    *(float4*)dst       = make_float4(v[0], v[1], v[2], v[3]);
    *(float4*)(dst + 4) = make_float4(v[4], v[5], v[6], v[7]);
}

// One recurrent layer. grid = HID blocks x 512 thr; block = 1 neuron,
// wave = 1 branch row (lane = batch). Streams come prepacked from k_pack.
// MODE 0: dense x from xT2[i][lane][TP]. MODE 1: spike masks inm[i*TP+t].
template <int DIN, int NNZ, int MODE, int RSTRIDE, int WOFF>
__global__ __launch_bounds__(512, 8) void k_layer(
    const uint8_t* __restrict__ pk,         // packed streams
    const float* __restrict__ bias,         // [HID*NBR]
    const float* __restrict__ tau_m,        // [HID]
    const float* __restrict__ tau_n,        // [HID*NBR]
    const float* __restrict__ xin,          // MODE0: [DIN][64][TP]
    const uint64_t* __restrict__ inm,       // MODE1: [DIN][TP]
    uint64_t* __restrict__ outm)            // [HID][TP]
{
    const int lane = threadIdx.x & 63;
    const int wid  = __builtin_amdgcn_readfirstlane(threadIdx.x >> 6); // 0..7
    const int h    = blockIdx.x;
    const int r    = h * NBR + wid;

    __shared__ float red[2][NBR * CH * 64];

    const uint8_t*  pkrow = pk + (size_t)r * RSTRIDE;
    const uint32_t* idxp  = (const uint32_t*)pkrow;          // u16 pairs
    const float*    wp    = (const float*)(pkrow + WOFF);
    inm = (const uint64_t*)__builtin_assume_aligned(inm, 64);

    const float be = 1.f / (1.f + expf(-tau_n[r]));
    const float om = 1.f - be;
    const float bb = bias[r];
    const float al  = 1.f / (1.f + expf(-tau_m[h]));
    const float oma = 1.f - al;

    float d = 0.f, mem = 0.f, spkprev = 0.f;

    for (int tc = 0; tc < NCHUNK; ++tc) {
        const int t0  = tc * CH;
        const int buf = tc & 1;
        float a[CH];
#pragma unroll
        for (int k = 0; k < CH; ++k) a[k] = 0.f;

        if constexpr (MODE == 1) {
            for (int jj = 0; jj < NNZ / 2; ++jj) {
                const uint32_t pair = idxp[jj];
                const int ix0 = (int)(pair & 0xffffu);
                const int ix1 = (int)(pair >> 16);
                const float2 wpair = ((const float2*)wp)[jj];
                const float w0 = wpair.x, w1 = wpair.y;
                const ulonglong4* p0 =
                    (const ulonglong4*)(inm + (size_t)ix0 * TP + t0);
                const ulonglong4* p1 =
                    (const ulonglong4*)(inm + (size_t)ix1 * TP + t0);
                const ulonglong4 a0 = p0[0], b0 = p0[1];
                const ulonglong4 a1 = p1[0], b1 = p1[1];
                const uint64_t m0[CH] = {a0.x, a0.y, a0.z, a0.w,
                                         b0.x, b0.y, b0.z, b0.w};
                const uint64_t m1[CH] = {a1.x, a1.y, a1.z, a1.w,
                                         b1.x, b1.y, b1.z, b1.w};
#pragma unroll
                for (int k = 0; k < CH; ++k) {
                    float s0, s1;
                    asm("v_cndmask_b32 %0, 0, %1, %2"
                        : "=v"(s0) : "v"(w0), "s"(m0[k]));
                    a[k] += s0;
                    asm("v_cndmask_b32 %0, 0, %1, %2"
                        : "=v"(s1) : "v"(w1), "s"(m1[k]));
                    a[k] += s1;
                }
            }
        } else {
            for (int jj = 0; jj < NNZ / 2; ++jj) {
                const uint32_t pair = idxp[jj];
                const int ix0 = (int)(pair & 0xffffu);
                const int ix1 = (int)(pair >> 16);
                const float2 wpair = ((const float2*)wp)[jj];
                const float w0 = wpair.x, w1 = wpair.y;
                const float* q0 = xin + (size_t)ix0 * (64 * TP) + lane * TP + t0;
                const float* q1 = xin + (size_t)ix1 * (64 * TP) + lane * TP + t0;
                const float4 xa0 = *(const float4*)q0;
                const float4 xb0 = *(const float4*)(q0 + 4);
                const float4 xa1 = *(const float4*)q1;
                const float4 xb1 = *(const float4*)(q1 + 4);
                a[0] += w0 * xa0.x; a[1] += w0 * xa0.y;
                a[2] += w0 * xa0.z; a[3] += w0 * xa0.w;
                a[4] += w0 * xb0.x; a[5] += w0 * xb0.y;
                a[6] += w0 * xb0.z; a[7] += w0 * xb0.w;
                a[0] += w1 * xa1.x; a[1] += w1 * xa1.y;
                a[2] += w1 * xa1.z; a[3] += w1 * xa1.w;
                a[4] += w1 * xb1.x; a[5] += w1 * xb1.y;
                a[6] += w1 * xb1.z; a[7] += w1 * xb1.w;
            }
        }

        // branch decay (sequential within chunk), stash per-row d
#pragma unroll
        for (int k = 0; k < CH; ++k) {
            d = be * d + om * (a[k] + bb);
            red[buf][(wid * CH + k) * 64 + lane] = d;
        }
        // one barrier per chunk: waves 1..7 run chunk tc+1 into buf^1 while
        // wave 0 reduces buf.
        __syncthreads();

        if (wid == 0) {
#pragma unroll
            for (int k = 0; k < CH; ++k) {
                const float r0 = red[buf][(0 * CH + k) * 64 + lane];
                const float r1 = red[buf][(1 * CH + k) * 64 + lane];
                const float r2 = red[buf][(2 * CH + k) * 64 + lane];
                const float r3 = red[buf][(3 * CH + k) * 64 + lane];
                const float r4 = red[buf][(4 * CH + k) * 64 + lane];
                const float r5 = red[buf][(5 * CH + k) * 64 + lane];
                const float r6 = red[buf][(6 * CH + k) * 64 + lane];
                const float r7 = red[buf][(7 * CH + k) * 64 + lane];
                const float p01 = r0 + r1, p23 = r2 + r3;
                const float p45 = r4 + r5, p67 = r6 + r7;
                const float l = ((p01 + p23) + p45) + p67;
                if (t0 + k < TT) {
                    mem = al * mem + oma * l - spkprev;   // VTH = 1.0
                    spkprev = (mem > 1.0f) ? 1.f : 0.f;
                    const unsigned long long bal = __ballot(mem > 1.0f);
                    if (lane == 0) outm[(size_t)h * TP + (t0 + k)] = bal;
                }
            }
        }
    }
}

// Y[t][o][b] = wr[o] . s3(t,:,b); 4 waves split i (linear readout — reorder
// safe). wid through readfirstlane so mask addresses stay scalar.
__global__ __launch_bounds__(256) void k_ry(const float* __restrict__ wr,
                                            const uint64_t* __restrict__ s3m,
                                            float* __restrict__ Y) {
    const int lane  = threadIdx.x & 63;
    const int wid   = __builtin_amdgcn_readfirstlane(threadIdx.x >> 6); // 0..3
    const int o  = blockIdx.x / NCHUNK;
    const int t0 = (blockIdx.x % NCHUNK) * CH;
    s3m = (const uint64_t*)__builtin_assume_aligned(s3m, 64);
    const float* wrow = wr + (size_t)o * HID;
    __shared__ float red[4 * CH * 64];
    float acc[CH];
#pragma unroll
    for (int k = 0; k < CH; ++k) acc[k] = 0.f;
#pragma unroll 4
    for (int ii = 0; ii < HID / 4; ++ii) {
        const int i = wid * (HID / 4) + ii;
        const float wv = wrow[i];
        const ulonglong4* p = (const ulonglong4*)(s3m + (size_t)i * TP + t0);
        const ulonglong4 ma = p[0], mb = p[1];
        const uint64_t m[CH] = {ma.x, ma.y, ma.z, ma.w, mb.x, mb.y, mb.z, mb.w};
#pragma unroll
        for (int k = 0; k < CH; ++k) {
            float s;
            asm("v_cndmask_b32 %0, 0, %1, %2" : "=v"(s) : "v"(wv), "s"(m[k]));
            acc[k] += s;
        }
    }
#pragma unroll
    for (int k = 0; k < CH; ++k)
        red[(wid * CH + k) * 64 + lane] = acc[k];
    __syncthreads();
    if (wid == 0) {
#pragma unroll
        for (int k = 0; k < CH; ++k) {
            if (t0 + k >= TT) break;
            const float v = ((red[(0 * CH + k) * 64 + lane]
                            + red[(1 * CH + k) * 64 + lane])
                            + red[(2 * CH + k) * 64 + lane])
                            + red[(3 * CH + k) * 64 + lane];
            Y[((size_t)(t0 + k) * OUTN + o) * 64 + lane] = v;
        }
    }
}

// acc[o][b] = sum_t (Y + br[o]) * (1 - ar^(150-t))   (closed-form mr scan)
__global__ void k_racc(const float* __restrict__ Y,
                       const float* __restrict__ br,
                       const float* __restrict__ tau_mr,
                       float* __restrict__ ACC) {
    const int o = blockIdx.x, lane = threadIdx.x;
    const float ar  = 1.f / (1.f + expf(-tau_mr[o]));
    const float bro = br[o];
    float acc = 0.f, q = ar;
    for (int t = TT - 1; t >= 0; --t) {
        const float y = Y[((size_t)t * OUTN + o) * 64 + lane] + bro;
        acc += y * (1.f - q);
        q *= ar;
    }
    ACC[o * 64 + lane] = acc;
}

__global__ void k_smax(const float* __restrict__ ACC, float* __restrict__ out) {
    const int b = threadIdx.x;   // 64 threads
    float v[OUTN];
    float mx = -3.4e38f;
    for (int o = 0; o < OUTN; ++o) {
        v[o] = ACC[o * 64 + b] / (float)TT;
        mx = fmaxf(mx, v[o]);
    }
    float sum = 0.f;
    for (int o = 0; o < OUTN; ++o) sum += expf(v[o] - mx);
    const float lse = mx + logf(sum);
    for (int o = 0; o < OUTN; ++o) out[b * OUTN + o] = v[o] - lse;
}

extern "C" void kernel_launch(void* const* d_in, const int* in_sizes, int n_in,
                              void* d_out, int out_size, void* d_ws,
                              size_t ws_size, hipStream_t stream) {
    (void)in_sizes; (void)n_in; (void)out_size; (void)ws_size;
    const float* x   = (const float*)d_in[0];
    const float* w1  = (const float*)d_in[1];
    const float* b1  = (const float*)d_in[2];
    const float* tm1 = (const float*)d_in[3];
    const float* tn1 = (const float*)d_in[4];
    const float* w2  = (const float*)d_in[5];
    const float* b2  = (const float*)d_in[6];
    const float* tm2 = (const float*)d_in[7];
    const float* tn2 = (const float*)d_in[8];
    const float* w3  = (const float*)d_in[9];
    const float* b3  = (const float*)d_in[10];
    const float* tm3 = (const float*)d_in[11];
    const float* tn3 = (const float*)d_in[12];
    const float* wr  = (const float*)d_in[13];
    const float* br  = (const float*)d_in[14];
    const float* tmr = (const float*)d_in[15];
    const void*  m1  = d_in[16];
    const void*  m2  = d_in[17];
    const void*  m3  = d_in[18];
    float* out = (float*)d_out;

    char* ws = (char*)d_ws;
    uint64_t* sA  = (uint64_t*)(ws + SA_OFF);   // s1m, later s3m
    uint64_t* sB  = (uint64_t*)(ws + SB_OFF);   // s2m
    uint8_t*  PK  = (uint8_t*)(ws + PK_OFF);    // PK1 / PK2 / PK3
    float*    xT2 = (float*)(ws + XT_OFF);
    float*    Y   = (float*)(ws + Y_OFF);
    float*    ACC = (float*)(ws + ACC_OFF);

    // layer 1 (dense input)
    k_pack<INSZ, 15, 16, 128, 32><<<HID, 512, 0, stream>>>(w1, m1, PK);
    k_tx2<<<570, 256, 0, stream>>>(x, xT2);
    k_layer<INSZ, 16, 0, 128, 32><<<HID, 512, 0, stream>>>(
        PK, b1, tm1, tn1, xT2, nullptr, sA);
    // layer 2 (PK slot reused; xT2/PK1 dead)
    k_pack<HID, 128, 128, 768, 256><<<HID, 512, 0, stream>>>(w2, m2, PK);
    k_layer<HID, 128, 1, 768, 256><<<HID, 512, 0, stream>>>(
        PK, b2, tm2, tn2, nullptr, sA, sB);
    // layer 3 (PK reused again; s3m over dead s1m)
    k_pack<HID, 128, 128, 768, 256><<<HID, 512, 0, stream>>>(w3, m3, PK);
    k_layer<HID, 128, 1, 768, 256><<<HID, 512, 0, stream>>>(
        PK, b3, tm3, tn3, nullptr, sB, sA);
    // readout (Y over dead PK)
    k_ry<<<OUTN * NCHUNK, 256, 0, stream>>>(wr, sA, Y);
    k_racc<<<OUTN, 64, 0, stream>>>(Y, br, tmr, ACC);
    k_smax<<<1, 64, 0, stream>>>(ACC, out);
}

// Round 7
// 1666.032 us; speedup vs baseline: 1.4585x; 1.4585x over previous
//
#include <hip/hip_runtime.h>
#include <stdint.h>

#define TT     150
#define INSZ   120
#define HID    1024
#define OUTN   35
#define NBR    8
#define TP     152     // padded time steps (19*8); mask row = 1216 B (64-aligned)
#define CH     8
#define NCHUNK 19

// ---------------- ws map (bytes) — aliased, peak 8.78 MB (verified r6) ----
// SA: s1m (layer1 out) then s3m (layer3 out)   [1024][152] u64 = 1,245,184
// SB: s2m                                       1,245,184
// PK: pack slot @2,490,368: PK1 (1 MB) then PK2/PK3 (6,291,456 each, reused)
// XT: xT [150][120][64] f32 = 4,608,000 @3,538,944 (after PK1, dead pre-PK2)
// Y : over dead PK after layer3; ACC after Y.
#define SA_OFF   0
#define SB_OFF   1245184
#define PK_OFF   2490368
#define XT_OFF   3538944
#define Y_OFF    2490368
#define ACC_OFF  3866624

// ---- pack masked rows into {idx u16[NNZ_OUT], w f32[NNZ_OUT]} streams ----
template <int DIN, int NNZ_EXPECT, int NNZ_OUT, int RSTRIDE, int WOFF>
__global__ __launch_bounds__(512) void k_pack(
    const float* __restrict__ w, const void* __restrict__ maskp,
    uint8_t* __restrict__ dst) {
    const int lane = threadIdx.x & 63;
    const int wid  = __builtin_amdgcn_readfirstlane(threadIdx.x >> 6);
    const int r    = blockIdx.x * 8 + wid;
    uint16_t* di = (uint16_t*)(dst + (size_t)r * RSTRIDE);
    float*    dw = (float*)(dst + (size_t)r * RSTRIDE + WOFF);
    const unsigned char* m8  = (const unsigned char*)maskp;
    const int*           m32 = (const int*)maskp;

    int cnt = 0;
    for (int c = 0; c * 64 < DIN; ++c) {
        const int i = c * 64 + lane;
        int   mv = 0; float wv = 0.f;
        if (i < DIN) { mv = m8[(size_t)r * DIN + i]; wv = w[(size_t)r * DIN + i]; }
        const unsigned long long bal = __ballot(mv != 0);
        const int pos = __popcll(bal & ((1ull << lane) - 1ull));
        if (mv && cnt + pos < NNZ_OUT) { di[cnt + pos] = (uint16_t)i; dw[cnt + pos] = wv; }
        cnt += __popcll(bal);
    }
    if (cnt != NNZ_EXPECT) {          // masks are int32 after all
        cnt = 0;
        for (int c = 0; c * 64 < DIN; ++c) {
            const int i = c * 64 + lane;
            int   mv = 0; float wv = 0.f;
            if (i < DIN) { mv = m32[(size_t)r * DIN + i]; wv = w[(size_t)r * DIN + i]; }
            const unsigned long long bal = __ballot(mv != 0);
            const int pos = __popcll(bal & ((1ull << lane) - 1ull));
            if (mv && cnt + pos < NNZ_OUT) { di[cnt + pos] = (uint16_t)i; dw[cnt + pos] = wv; }
            cnt += __popcll(bal);
        }
    }
    for (int f = cnt + lane; f < NNZ_OUT; f += 64) { di[f] = 0; dw[f] = 0.f; }
}

// transpose x[b][0][t][i] -> xT[t][i][b], LDS-tiled (both sides coalesced)
__global__ __launch_bounds__(256) void k_tx(const float* __restrict__ x,
                                            float* __restrict__ xT) {
    const int t = blockIdx.x;
    __shared__ float tile[INSZ * 65];
    for (int e = threadIdx.x; e < INSZ * 64; e += 256) {
        const int b = e / INSZ, i = e - b * INSZ;
        tile[i * 65 + b] = x[((size_t)b * TT + t) * INSZ + i];
    }
    __syncthreads();
    for (int e = threadIdx.x; e < INSZ * 64; e += 256) {
        const int i = e >> 6, b = e & 63;
        xT[((size_t)t * INSZ + i) * 64 + b] = tile[i * 65 + b];
    }
}

// One recurrent layer. grid = HID blocks x 512 thr; block = 1 neuron,
// wave = 1 branch row (lane = batch). Row streams prepacked by k_pack,
// staged into LDS ent[] once (coalesced), then the PROVEN r5 inner loop:
// ds_read_b64 -> readfirstlane(idx) -> scalar mask loads -> cndmask ("s").
// MODE 0: dense x from xT[t][i][64]. MODE 1: spike masks inm[i*TP+t].
template <int DIN, int NNZ, int MODE, int RSTRIDE, int WOFF>
__global__ __launch_bounds__(512, 8) void k_layer(
    const uint8_t* __restrict__ pk,         // packed streams
    const float* __restrict__ bias,         // [HID*NBR]
    const float* __restrict__ tau_m,        // [HID]
    const float* __restrict__ tau_n,        // [HID*NBR]
    const float* __restrict__ xin,          // MODE0: [T][DIN][64]
    const uint64_t* __restrict__ inm,       // MODE1: [DIN][TP]
    uint64_t* __restrict__ outm)            // [HID][TP]
{
    const int lane = threadIdx.x & 63;
    const int wid  = __builtin_amdgcn_readfirstlane(threadIdx.x >> 6); // 0..7
    const int h    = blockIdx.x;
    const int r    = h * NBR + wid;

    __shared__ uint2 ent[NBR * NNZ];        // (w bits, idx) per row
    __shared__ float red[2][NBR * CH * 64]; // double-buffered partial sums

    inm = (const uint64_t*)__builtin_assume_aligned(inm, 64);

    // ---- coalesced LDS fill from the packed row ----
    {
        const uint16_t* pidx = (const uint16_t*)(pk + (size_t)r * RSTRIDE);
        const float*    pw   = (const float*)(pk + (size_t)r * RSTRIDE + WOFF);
        for (int s = lane; s < NNZ; s += 64)
            ent[wid * NNZ + s] = make_uint2(__float_as_uint(pw[s]),
                                            (unsigned)pidx[s]);
    }
    __syncthreads();

    const float be = 1.f / (1.f + expf(-tau_n[r]));
    const float om = 1.f - be;
    const float bb = bias[r];
    const float al  = 1.f / (1.f + expf(-tau_m[h]));
    const float oma = 1.f - al;

    float d = 0.f, mem = 0.f, spkprev = 0.f;
    const int base = wid * NNZ;

    for (int tc = 0; tc < NCHUNK; ++tc) {
        const int t0  = tc * CH;
        const int buf = tc & 1;
        float a[CH];
#pragma unroll
        for (int k = 0; k < CH; ++k) a[k] = 0.f;

        if constexpr (MODE == 1) {
#pragma unroll 4
            for (int j = 0; j < NNZ; ++j) {
                const uint2 e  = ent[base + j];
                const int   ix = __builtin_amdgcn_readfirstlane((int)e.y);
                const float wv = __uint_as_float(e.x);
                const ulonglong4* p =
                    (const ulonglong4*)(inm + (size_t)ix * TP + t0);
                const ulonglong4 ma = p[0], mb = p[1];
                const uint64_t m[CH] = {ma.x, ma.y, ma.z, ma.w,
                                        mb.x, mb.y, mb.z, mb.w};
#pragma unroll
                for (int k = 0; k < CH; ++k) {
                    float s;
                    asm("v_cndmask_b32 %0, 0, %1, %2"
                        : "=v"(s) : "v"(wv), "s"(m[k]));
                    a[k] += s;
                }
            }
        } else {
            const float* xb = xin + (size_t)t0 * DIN * 64;
#pragma unroll 4
            for (int j = 0; j < NNZ; ++j) {
                const uint2 e  = ent[base + j];
                const int   ix = __builtin_amdgcn_readfirstlane((int)e.y);
                const float wv = __uint_as_float(e.x);
#pragma unroll
                for (int k = 0; k < CH; ++k)
                    a[k] += wv * xb[((size_t)k * DIN + ix) * 64 + lane];
            }
        }

        // branch decay (sequential within chunk), stash per-row d
#pragma unroll
        for (int k = 0; k < CH; ++k) {
            d = be * d + om * (a[k] + bb);
            red[buf][(wid * CH + k) * 64 + lane] = d;
        }
        // one barrier per chunk: waves 1..7 run chunk tc+1 into buf^1 while
        // wave 0 reduces buf.
        __syncthreads();

        if (wid == 0) {
#pragma unroll
            for (int k = 0; k < CH; ++k) {
                // EXACT reference pair order
                const float r0 = red[buf][(0 * CH + k) * 64 + lane];
                const float r1 = red[buf][(1 * CH + k) * 64 + lane];
                const float r2 = red[buf][(2 * CH + k) * 64 + lane];
                const float r3 = red[buf][(3 * CH + k) * 64 + lane];
                const float r4 = red[buf][(4 * CH + k) * 64 + lane];
                const float r5 = red[buf][(5 * CH + k) * 64 + lane];
                const float r6 = red[buf][(6 * CH + k) * 64 + lane];
                const float r7 = red[buf][(7 * CH + k) * 64 + lane];
                const float p01 = r0 + r1, p23 = r2 + r3;
                const float p45 = r4 + r5, p67 = r6 + r7;
                const float l = ((p01 + p23) + p45) + p67;
                if (t0 + k < TT) {
                    mem = al * mem + oma * l - spkprev;   // VTH = 1.0
                    spkprev = (mem > 1.0f) ? 1.f : 0.f;
                    const unsigned long long bal = __ballot(mem > 1.0f);
                    if (lane == 0) outm[(size_t)h * TP + (t0 + k)] = bal;
                }
            }
        }
    }
}

// Y[t][o][b] = wr[o] . s3(t,:,b); 4 waves split i (linear readout — reorder
// safe). wid through readfirstlane so mask addresses stay scalar.
__global__ __launch_bounds__(256) void k_ry(const float* __restrict__ wr,
                                            const uint64_t* __restrict__ s3m,
                                            float* __restrict__ Y) {
    const int lane  = threadIdx.x & 63;
    const int wid   = __builtin_amdgcn_readfirstlane(threadIdx.x >> 6); // 0..3
    const int o  = blockIdx.x / NCHUNK;
    const int t0 = (blockIdx.x % NCHUNK) * CH;
    s3m = (const uint64_t*)__builtin_assume_aligned(s3m, 64);
    const float* wrow = wr + (size_t)o * HID;
    __shared__ float red[4 * CH * 64];
    float acc[CH];
#pragma unroll
    for (int k = 0; k < CH; ++k) acc[k] = 0.f;
#pragma unroll 4
    for (int ii = 0; ii < HID / 4; ++ii) {
        const int i = wid * (HID / 4) + ii;
        const float wv = wrow[i];
        const ulonglong4* p = (const ulonglong4*)(s3m + (size_t)i * TP + t0);
        const ulonglong4 ma = p[0], mb = p[1];
        const uint64_t m[CH] = {ma.x, ma.y, ma.z, ma.w, mb.x, mb.y, mb.z, mb.w};
#pragma unroll
        for (int k = 0; k < CH; ++k) {
            float s;
            asm("v_cndmask_b32 %0, 0, %1, %2" : "=v"(s) : "v"(wv), "s"(m[k]));
            acc[k] += s;
        }
    }
#pragma unroll
    for (int k = 0; k < CH; ++k)
        red[(wid * CH + k) * 64 + lane] = acc[k];
    __syncthreads();
    if (wid == 0) {
#pragma unroll
        for (int k = 0; k < CH; ++k) {
            if (t0 + k >= TT) break;
            const float v = ((red[(0 * CH + k) * 64 + lane]
                            + red[(1 * CH + k) * 64 + lane])
                            + red[(2 * CH + k) * 64 + lane])
                            + red[(3 * CH + k) * 64 + lane];
            Y[((size_t)(t0 + k) * OUTN + o) * 64 + lane] = v;
        }
    }
}

// acc[o][b] = sum_t (Y + br[o]) * (1 - ar^(150-t))   (closed-form mr scan)
__global__ void k_racc(const float* __restrict__ Y,
                       const float* __restrict__ br,
                       const float* __restrict__ tau_mr,
                       float* __restrict__ ACC) {
    const int o = blockIdx.x, lane = threadIdx.x;
    const float ar  = 1.f / (1.f + expf(-tau_mr[o]));
    const float bro = br[o];
    float acc = 0.f, q = ar;
    for (int t = TT - 1; t >= 0; --t) {
        const float y = Y[((size_t)t * OUTN + o) * 64 + lane] + bro;
        acc += y * (1.f - q);
        q *= ar;
    }
    ACC[o * 64 + lane] = acc;
}

__global__ void k_smax(const float* __restrict__ ACC, float* __restrict__ out) {
    const int b = threadIdx.x;   // 64 threads
    float v[OUTN];
    float mx = -3.4e38f;
    for (int o = 0; o < OUTN; ++o) {
        v[o] = ACC[o * 64 + b] / (float)TT;
        mx = fmaxf(mx, v[o]);
    }
    float sum = 0.f;
    for (int o = 0; o < OUTN; ++o) sum += expf(v[o] - mx);
    const float lse = mx + logf(sum);
    for (int o = 0; o < OUTN; ++o) out[b * OUTN + o] = v[o] - lse;
}

extern "C" void kernel_launch(void* const* d_in, const int* in_sizes, int n_in,
                              void* d_out, int out_size, void* d_ws,
                              size_t ws_size, hipStream_t stream) {
    (void)in_sizes; (void)n_in; (void)out_size; (void)ws_size;
    const float* x   = (const float*)d_in[0];
    const float* w1  = (const float*)d_in[1];
    const float* b1  = (const float*)d_in[2];
    const float* tm1 = (const float*)d_in[3];
    const float* tn1 = (const float*)d_in[4];
    const float* w2  = (const float*)d_in[5];
    const float* b2  = (const float*)d_in[6];
    const float* tm2 = (const float*)d_in[7];
    const float* tn2 = (const float*)d_in[8];
    const float* w3  = (const float*)d_in[9];
    const float* b3  = (const float*)d_in[10];
    const float* tm3 = (const float*)d_in[11];
    const float* tn3 = (const float*)d_in[12];
    const float* wr  = (const float*)d_in[13];
    const float* br  = (const float*)d_in[14];
    const float* tmr = (const float*)d_in[15];
    const void*  m1  = d_in[16];
    const void*  m2  = d_in[17];
    const void*  m3  = d_in[18];
    float* out = (float*)d_out;

    char* ws = (char*)d_ws;
    uint64_t* sA  = (uint64_t*)(ws + SA_OFF);   // s1m, later s3m
    uint64_t* sB  = (uint64_t*)(ws + SB_OFF);   // s2m
    uint8_t*  PK  = (uint8_t*)(ws + PK_OFF);    // PK1 / PK2 / PK3
    float*    xT  = (float*)(ws + XT_OFF);
    float*    Y   = (float*)(ws + Y_OFF);
    float*    ACC = (float*)(ws + ACC_OFF);

    // layer 1 (dense input)
    k_pack<INSZ, 15, 16, 128, 32><<<HID, 512, 0, stream>>>(w1, m1, PK);
    k_tx<<<TT, 256, 0, stream>>>(x, xT);
    k_layer<INSZ, 16, 0, 128, 32><<<HID, 512, 0, stream>>>(
        PK, b1, tm1, tn1, xT, nullptr, sA);
    // layer 2 (PK slot reused; xT/PK1 dead after these two)
    k_pack<HID, 128, 128, 768, 256><<<HID, 512, 0, stream>>>(w2, m2, PK);
    k_layer<HID, 128, 1, 768, 256><<<HID, 512, 0, stream>>>(
        PK, b2, tm2, tn2, nullptr, sA, sB);
    // layer 3 (PK reused again; s3m over dead s1m)
    k_pack<HID, 128, 128, 768, 256><<<HID, 512, 0, stream>>>(w3, m3, PK);
    k_layer<HID, 128, 1, 768, 256><<<HID, 512, 0, stream>>>(
        PK, b3, tm3, tn3, nullptr, sB, sA);
    // readout (Y over dead PK)
    k_ry<<<OUTN * NCHUNK, 256, 0, stream>>>(wr, sA, Y);
    k_racc<<<OUTN, 64, 0, stream>>>(Y, br, tmr, ACC);
    k_smax<<<1, 64, 0, stream>>>(ACC, out);
}